// Round 2
// baseline (603.717 us; speedup 1.0000x reference)
//
#include <hip/hip_runtime.h>
#include <math.h>

// Problem constants (fixed by reference)
#define NN   10000
#define EE   160000
#define GG   128
#define HIDK 25
#define KE   26      // 25 MLP features + 1 constant row for b2
#define DOUT 32
#define EPSBN 1e-5f

// ---------------- workspace layout (float offsets) ----------------
// zeroed region (one hipMemsetAsync):
#define OFF_MO    0          // 9 used
#define OFF_DEG   16         // N
#define OFF_AGG0  10016      // N*32
#define OFF_AGG1  330016     // N*32
#define OFF_GSUM  650016     // G*32
#define OFF_GCNT  654112     // G
#define ZERO_FLOATS 654240
// non-zeroed:
#define OFF_W1F   654240     // 75 (padded 80)
#define OFF_B1F   654320     // 25 (padded 32)
#define OFF_Z     654352     // N*26*32 = 8,320,000
#define OFF_X1    8974352    // N*32
#define OFF_X2    9294352    // N*32
#define TOTAL_FLOATS 9614352 // ~38.5 MB of d_ws

__device__ inline float wave_red(float v) {
    for (int off = 32; off; off >>= 1) v += __shfl_down(v, off);
    return v;
}

// ---- edge_attr moments: s1[c], s2[c,d]
__global__ void k_moments(const float* __restrict__ ea, float* __restrict__ mo) {
    float s[9];
#pragma unroll
    for (int j = 0; j < 9; j++) s[j] = 0.f;
    int stride = gridDim.x * blockDim.x;
    for (int e = blockIdx.x * blockDim.x + threadIdx.x; e < EE; e += stride) {
        float a0 = ea[3 * e], a1 = ea[3 * e + 1], a2 = ea[3 * e + 2];
        s[0] += a0; s[1] += a1; s[2] += a2;
        s[3] += a0 * a0; s[4] += a0 * a1; s[5] += a0 * a2;
        s[6] += a1 * a1; s[7] += a1 * a2; s[8] += a2 * a2;
    }
#pragma unroll
    for (int j = 0; j < 9; j++) {
        float r = wave_red(s[j]);
        if ((threadIdx.x & 63) == 0) atomicAdd(mo + j, r);
    }
}

// ---- in-degree (dst) counts
__global__ void k_deg(const int* __restrict__ ei, float* __restrict__ deg) {
    int e = blockIdx.x * blockDim.x + threadIdx.x;
    if (e < EE) atomicAdd(deg + ei[EE + e], 1.0f);
}

// ---- fold BN (analytic stats) into w1', b1'
__global__ void k_fold(const float* __restrict__ mo, const float* __restrict__ w1,
                       const float* __restrict__ b1, const float* __restrict__ g,
                       const float* __restrict__ be, float* __restrict__ w1f,
                       float* __restrict__ b1f) {
    int j = threadIdx.x;
    if (j >= HIDK) return;
    const float inv = 1.0f / (float)EE;
    float m0 = mo[0] * inv, m1 = mo[1] * inv, m2 = mo[2] * inv;
    float c00 = mo[3] * inv - m0 * m0, c01 = mo[4] * inv - m0 * m1, c02 = mo[5] * inv - m0 * m2;
    float c11 = mo[6] * inv - m1 * m1, c12 = mo[7] * inv - m1 * m2, c22 = mo[8] * inv - m2 * m2;
    float w0 = w1[j], wa = w1[25 + j], wb = w1[50 + j];
    float mean = m0 * w0 + m1 * wa + m2 * wb + b1[j];
    float var = w0 * w0 * c00 + wa * wa * c11 + wb * wb * c22
              + 2.f * (w0 * wa * c01 + w0 * wb * c02 + wa * wb * c12);
    float sc = g[j] * rsqrtf(var + EPSBN);
    w1f[j] = w0 * sc; w1f[25 + j] = wa * sc; w1f[50 + j] = wb * sc;
    b1f[j] = (b1[j] - mean) * sc + be[j];
}

// ---- per-node z[n,k,o] = sum_i x[n,i]*w2[k,i,o]; row 25 = x@b2
// Restructured (R1): x tile in LDS (broadcast reads), w2 column in registers,
// 16 independent accumulators -> no dependent-load chains.
// Block = 256 threads = 32 o-lanes x 8 k-groups; TILE_N=16 (10000/16=625 blocks).
template <int DIN>
__global__ void k_z(const float* __restrict__ x, const float* __restrict__ w2,
                    const float* __restrict__ b2, float* __restrict__ z) {
    __shared__ float xs[16][DIN];
    int t = threadIdx.x;
    int n0 = blockIdx.x * 16;
    // cooperative coalesced x-tile load (NN % 16 == 0, no tail guard needed)
    const int NLOAD = 16 * DIN;
#pragma unroll
    for (int idx = t; idx < NLOAD; idx += 256) {
        int n = idx / DIN, i = idx % DIN;
        xs[n][i] = x[(n0 + n) * DIN + i];
    }
    __syncthreads();
    int o = t & 31, kq = t >> 5;
    for (int k = kq; k < KE; k += 8) {
        float w[DIN];
        if (k < HIDK) {
#pragma unroll
            for (int i = 0; i < DIN; i++) w[i] = w2[(k * DIN + i) * DOUT + o];
        } else {
#pragma unroll
            for (int i = 0; i < DIN; i++) w[i] = b2[i * DOUT + o];
        }
        float* zp = z + (size_t)n0 * (KE * DOUT) + k * DOUT + o;
#pragma unroll
        for (int n = 0; n < 16; n++) {
            float acc = 0.f;
#pragma unroll
            for (int i = 0; i < DIN; i++) acc += xs[n][i] * w[i];
            zp[n * (KE * DOUT)] = acc;
        }
    }
}

// ---- edge kernel: h = relu(ea@w1'+b1'); msg = h . z[src]; atomic scatter to agg[dst]
__global__ void k_edge(const float* __restrict__ ea, const int* __restrict__ ei,
                       const float* __restrict__ w1f, const float* __restrict__ b1f,
                       const float* __restrict__ z, float* __restrict__ agg) {
    __shared__ float hsh[8][KE];
    __shared__ int ssrc[8], sdst[8];
    int t = threadIdx.x;
    int eb = blockIdx.x * 8;
    if (t < 8 * KE) {
        int el = t / KE, k = t - el * KE;
        int e = eb + el;
        float v = 1.0f;
        if (e < EE && k < HIDK) {
            v = ea[3 * e] * w1f[k] + ea[3 * e + 1] * w1f[25 + k] + ea[3 * e + 2] * w1f[50 + k] + b1f[k];
            v = v > 0.f ? v : 0.f;
        }
        hsh[el][k] = v;
    }
    if (t < 8) {
        int e = eb + t;
        ssrc[t] = (e < EE) ? ei[e] : 0;
        sdst[t] = (e < EE) ? ei[EE + e] : 0;
    }
    __syncthreads();
    int el = t >> 5, o = t & 31;
    int e = eb + el;
    if (e >= EE) return;
    const float* zp = z + (size_t)ssrc[el] * (KE * DOUT) + o;
    float acc = 0.f;
#pragma unroll
    for (int k = 0; k < KE; k++) acc += hsh[el][k] * zp[k * DOUT];
    atomicAdd(agg + sdst[el] * DOUT + o, acc);
}

// ---- node update: x_out = elu(agg/deg + x@wr + bc)
template <int DIN>
__global__ void k_node(const float* __restrict__ agg, const float* __restrict__ deg,
                       const float* __restrict__ xin, const float* __restrict__ wr,
                       const float* __restrict__ bc, float* __restrict__ xout) {
    int idx = blockIdx.x * blockDim.x + threadIdx.x;
    if (idx >= NN * DOUT) return;
    int n = idx >> 5, o = idx & 31;
    float d = deg[n]; d = d < 1.f ? 1.f : d;
    float acc = agg[idx] / d + bc[o];
#pragma unroll
    for (int i = 0; i < DIN; i++) acc += xin[n * DIN + i] * wr[i * DOUT + o];
    xout[idx] = acc > 0.f ? acc : expm1f(acc);
}

// ---- global mean pool accumulation
__global__ void k_pool(const float* __restrict__ x, const int* __restrict__ batch,
                       float* __restrict__ gsum, float* __restrict__ gcnt) {
    int idx = blockIdx.x * blockDim.x + threadIdx.x;
    if (idx >= NN * DOUT) return;
    int n = idx >> 5, o = idx & 31;
    int b = batch[n];
    atomicAdd(gsum + b * DOUT + o, x[idx]);
    if (o == 0) atomicAdd(gcnt + b, 1.0f);
}

// ---- final fc
__global__ void k_fc(const float* __restrict__ gsum, const float* __restrict__ gcnt,
                     const float* __restrict__ wfc, const float* __restrict__ bfc,
                     float* __restrict__ out) {
    int g = threadIdx.x;
    if (g >= GG) return;
    float c = gcnt[g]; c = c < 1.f ? 1.f : c;
    float acc = 0.f;
#pragma unroll
    for (int o = 0; o < DOUT; o++) acc += gsum[g * DOUT + o] * wfc[o];
    out[g] = acc / c + bfc[0];
}

extern "C" void kernel_launch(void* const* d_in, const int* in_sizes, int n_in,
                              void* d_out, int out_size, void* d_ws, size_t ws_size,
                              hipStream_t stream) {
    const float* x     = (const float*)d_in[0];
    const float* ea    = (const float*)d_in[1];
    const int*   ei    = (const int*)d_in[2];
    const int*   batch = (const int*)d_in[3];
    const float* w1_0 = (const float*)d_in[4];
    const float* b1_0 = (const float*)d_in[5];
    const float* g_0  = (const float*)d_in[6];
    const float* be_0 = (const float*)d_in[7];
    const float* w2_0 = (const float*)d_in[8];
    const float* b2_0 = (const float*)d_in[9];
    const float* wr_0 = (const float*)d_in[10];
    const float* bc_0 = (const float*)d_in[11];
    const float* w1_1 = (const float*)d_in[12];
    const float* b1_1 = (const float*)d_in[13];
    const float* g_1  = (const float*)d_in[14];
    const float* be_1 = (const float*)d_in[15];
    const float* w2_1 = (const float*)d_in[16];
    const float* b2_1 = (const float*)d_in[17];
    const float* wr_1 = (const float*)d_in[18];
    const float* bc_1 = (const float*)d_in[19];
    const float* wfc  = (const float*)d_in[20];
    const float* bfc  = (const float*)d_in[21];

    float* ws   = (float*)d_ws;
    float* mo   = ws + OFF_MO;
    float* deg  = ws + OFF_DEG;
    float* agg0 = ws + OFF_AGG0;
    float* agg1 = ws + OFF_AGG1;
    float* gsum = ws + OFF_GSUM;
    float* gcnt = ws + OFF_GCNT;
    float* w1f  = ws + OFF_W1F;
    float* b1f  = ws + OFF_B1F;
    float* z    = ws + OFF_Z;
    float* x1   = ws + OFF_X1;
    float* x2   = ws + OFF_X2;

    hipMemsetAsync(ws, 0, (size_t)ZERO_FLOATS * sizeof(float), stream);

    k_moments<<<256, 256, 0, stream>>>(ea, mo);
    k_deg<<<(EE + 255) / 256, 256, 0, stream>>>(ei, deg);

    // ---- layer 0 (din=16)
    k_fold<<<1, 64, 0, stream>>>(mo, w1_0, b1_0, g_0, be_0, w1f, b1f);
    k_z<16><<<NN / 16, 256, 0, stream>>>(x, w2_0, b2_0, z);
    k_edge<<<(EE + 7) / 8, 256, 0, stream>>>(ea, ei, w1f, b1f, z, agg0);
    k_node<16><<<(NN * DOUT + 255) / 256, 256, 0, stream>>>(agg0, deg, x, wr_0, bc_0, x1);

    // ---- layer 1 (din=32)
    k_fold<<<1, 64, 0, stream>>>(mo, w1_1, b1_1, g_1, be_1, w1f, b1f);
    k_z<32><<<NN / 16, 256, 0, stream>>>(x1, w2_1, b2_1, z);
    k_edge<<<(EE + 7) / 8, 256, 0, stream>>>(ea, ei, w1f, b1f, z, agg1);
    k_node<32><<<(NN * DOUT + 255) / 256, 256, 0, stream>>>(agg1, deg, x1, wr_1, bc_1, x2);

    // ---- pool + fc
    k_pool<<<(NN * DOUT + 255) / 256, 256, 0, stream>>>(x2, batch, gsum, gcnt);
    k_fc<<<1, 128, 0, stream>>>(gsum, gcnt, wfc, bfc, (float*)d_out);
}

// Round 3
// 513.514 us; speedup vs baseline: 1.1757x; 1.1757x over previous
//
#include <hip/hip_runtime.h>
#include <math.h>

// Problem constants (fixed by reference)
#define NN   10000
#define EE   160000
#define GG   128
#define HIDK 25
#define KE   26      // 25 MLP features + 1 constant row for b2
#define DOUT 32
#define EPSBN 1e-5f

// ---------------- workspace layout (float offsets) ----------------
// zeroed region (one hipMemsetAsync, ~97 KB):
#define OFF_CUR   0          // NN ints (scatter cursors)
#define OFF_GSUM  10016      // G*32
#define OFF_GCNT  14112      // G
#define OFF_DEGC  14240      // NN ints (degree counts)
#define ZERO_FLOATS 24256
// non-zeroed:
#define OFF_MOP   24256      // 64*12 moment partials
#define OFF_W1F   25024      // 75 (padded 80)
#define OFF_B1F   25104      // 25 (padded 32)
#define OFF_ROW   25136      // NN+1 ints (CSR row starts, padded 10016)
#define OFF_SRC   35152      // E ints (CSR src per slot)
#define OFF_EID   195152     // E ints (CSR edge id per slot)
#define OFF_Z     355152     // N*26*32 = 8,320,000
#define OFF_X1    8675152    // N*32
#define OFF_X2    8995152    // N*32
#define TOTAL_FLOATS 9315152 // ~37.3 MB of d_ws

__device__ inline float wave_red(float v) {
    for (int off = 32; off; off >>= 1) v += __shfl_down(v, off);
    return v;
}

// ---- stage 1: per-block moment partials (atomic-free; 64 blocks -> disjoint lines)
__global__ void k_moments(const float* __restrict__ ea, float* __restrict__ mop) {
    __shared__ float ls[4][9];
    float s[9];
#pragma unroll
    for (int j = 0; j < 9; j++) s[j] = 0.f;
    int t = threadIdx.x;
    for (int e = blockIdx.x * 256 + t; e < EE; e += 64 * 256) {
        float a0 = ea[3 * e], a1 = ea[3 * e + 1], a2 = ea[3 * e + 2];
        s[0] += a0; s[1] += a1; s[2] += a2;
        s[3] += a0 * a0; s[4] += a0 * a1; s[5] += a0 * a2;
        s[6] += a1 * a1; s[7] += a1 * a2; s[8] += a2 * a2;
    }
    int w = t >> 6, lane = t & 63;
#pragma unroll
    for (int j = 0; j < 9; j++) {
        float r = wave_red(s[j]);
        if (lane == 0) ls[w][j] = r;
    }
    __syncthreads();
    if (t < 9) {
        float r = ls[0][t] + ls[1][t] + ls[2][t] + ls[3][t];
        mop[blockIdx.x * 12 + t] = r;
    }
}

// ---- in-degree (dst) counts (int atomics, random 10k bins)
__global__ void k_deg(const int* __restrict__ ei, int* __restrict__ degc) {
    int e = blockIdx.x * blockDim.x + threadIdx.x;
    if (e < EE) atomicAdd(degc + ei[EE + e], 1);
}

// ---- single-block exclusive scan of degc -> row_start[NN+1]
__global__ void k_scan(const int* __restrict__ degc, int* __restrict__ row_start) {
    __shared__ int p[256];
    int t = threadIdx.x;
    const int CHUNK = 40;                 // 250*40 == 10000 exactly
    int base = t * CHUNK;
    int sum = 0;
    if (t < 250) {
        for (int i = 0; i < CHUNK; i++) sum += degc[base + i];
    }
    p[t] = sum;
    __syncthreads();
    for (int off = 1; off < 256; off <<= 1) {
        int v = (t >= off) ? p[t - off] : 0;
        __syncthreads();
        p[t] += v;
        __syncthreads();
    }
    int excl = p[t] - sum;
    if (t < 250) {
        int run = excl;
        for (int i = 0; i < CHUNK; i++) {
            row_start[base + i] = run;
            run += degc[base + i];
        }
    }
    if (t == 0) row_start[NN] = EE;
}

// ---- scatter edges into CSR slots
__global__ void k_scatter(const int* __restrict__ ei, const int* __restrict__ row_start,
                          int* __restrict__ cur, int* __restrict__ csr_src,
                          int* __restrict__ csr_eid) {
    int e = blockIdx.x * blockDim.x + threadIdx.x;
    if (e >= EE) return;
    int d = ei[EE + e];
    int pos = atomicAdd(cur + d, 1);
    int idx = row_start[d] + pos;
    csr_src[idx] = ei[e];
    csr_eid[idx] = e;
}

// ---- fold BN (analytic stats from partials) into w1', b1'
__global__ void k_fold(const float* __restrict__ mop, const float* __restrict__ w1,
                       const float* __restrict__ b1, const float* __restrict__ g,
                       const float* __restrict__ be, float* __restrict__ w1f,
                       float* __restrict__ b1f) {
    __shared__ float mo[9];
    int j = threadIdx.x;
    if (j < 9) {
        float s = 0.f;
        for (int b = 0; b < 64; b++) s += mop[b * 12 + j];
        mo[j] = s;
    }
    __syncthreads();
    if (j >= HIDK) return;
    const float inv = 1.0f / (float)EE;
    float m0 = mo[0] * inv, m1 = mo[1] * inv, m2 = mo[2] * inv;
    float c00 = mo[3] * inv - m0 * m0, c01 = mo[4] * inv - m0 * m1, c02 = mo[5] * inv - m0 * m2;
    float c11 = mo[6] * inv - m1 * m1, c12 = mo[7] * inv - m1 * m2, c22 = mo[8] * inv - m2 * m2;
    float w0 = w1[j], wa = w1[25 + j], wb = w1[50 + j];
    float mean = m0 * w0 + m1 * wa + m2 * wb + b1[j];
    float var = w0 * w0 * c00 + wa * wa * c11 + wb * wb * c22
              + 2.f * (w0 * wa * c01 + w0 * wb * c02 + wa * wb * c12);
    float sc = g[j] * rsqrtf(var + EPSBN);
    w1f[j] = w0 * sc; w1f[25 + j] = wa * sc; w1f[50 + j] = wb * sc;
    b1f[j] = (b1[j] - mean) * sc + be[j];
}

// ---- per-node z[n,k,o] = sum_i x[n,i]*w2[k,i,o]; row 25 = x@b2
// x tile in LDS (broadcast reads), w2 column in registers, 16 independent accumulators.
template <int DIN>
__global__ void k_z(const float* __restrict__ x, const float* __restrict__ w2,
                    const float* __restrict__ b2, float* __restrict__ z) {
    __shared__ float xs[16][DIN];
    int t = threadIdx.x;
    int n0 = blockIdx.x * 16;
    const int NLOAD = 16 * DIN;
#pragma unroll
    for (int idx = t; idx < NLOAD; idx += 256) {
        int n = idx / DIN, i = idx % DIN;
        xs[n][i] = x[(n0 + n) * DIN + i];
    }
    __syncthreads();
    int o = t & 31, kq = t >> 5;
    for (int k = kq; k < KE; k += 8) {
        float w[DIN];
        if (k < HIDK) {
#pragma unroll
            for (int i = 0; i < DIN; i++) w[i] = w2[(k * DIN + i) * DOUT + o];
        } else {
#pragma unroll
            for (int i = 0; i < DIN; i++) w[i] = b2[i * DOUT + o];
        }
        float* zp = z + (size_t)n0 * (KE * DOUT) + k * DOUT + o;
#pragma unroll
        for (int n = 0; n < 16; n++) {
            float acc = 0.f;
#pragma unroll
            for (int i = 0; i < DIN; i++) acc += xs[n][i] * w[i];
            zp[n * (KE * DOUT)] = acc;
        }
    }
}

// ---- fused CSR edge-gather + scatter-mean + root transform + ELU (no atomics)
// One wave per dst node: 64 lanes = 2 edge slots x 32 o-lanes.
template <int DIN>
__global__ void k_edgenode(const float* __restrict__ ea, const int* __restrict__ row_start,
                           const int* __restrict__ csr_src, const int* __restrict__ csr_eid,
                           const float* __restrict__ w1f, const float* __restrict__ b1f,
                           const float* __restrict__ z, const float* __restrict__ xin,
                           const float* __restrict__ wr, const float* __restrict__ bc,
                           float* __restrict__ xout) {
    int t = threadIdx.x;
    int wid = t >> 6;             // 4 waves/block
    int lane = t & 63;
    int j = lane >> 5, o = lane & 31;
    int n = blockIdx.x * 4 + wid; // grid 2500 -> n in [0,10000)
    int start = row_start[n];
    int cnt = row_start[n + 1] - start;
    float acc = 0.f;
    for (int p = j; p < cnt; p += 2) {
        int ce = csr_eid[start + p];   // broadcast load (same addr per half-wave)
        int cs = csr_src[start + p];
        float hv = 0.f;
        if (o < HIDK) {
            float a0 = ea[3 * ce], a1 = ea[3 * ce + 1], a2 = ea[3 * ce + 2];
            float v = a0 * w1f[o] + a1 * w1f[25 + o] + a2 * w1f[50 + o] + b1f[o];
            hv = v > 0.f ? v : 0.f;
        } else if (o == HIDK) {
            hv = 1.0f;                 // constant row folding b2
        }
        const float* zp = z + (size_t)cs * (KE * DOUT) + o;
        float a = 0.f;
#pragma unroll
        for (int k = 0; k < KE; k++) a += __shfl(hv, (j << 5) + k) * zp[k * DOUT];
        acc += a;
    }
    acc += __shfl_xor(acc, 32);        // combine the two edge slots
    if (j == 0) {
        float d = (float)cnt; if (d < 1.f) d = 1.f;
        float r = acc / d + bc[o];
#pragma unroll
        for (int i = 0; i < DIN; i++) r += xin[n * DIN + i] * wr[i * DOUT + o];
        r = r > 0.f ? r : expm1f(r);
        xout[n * DOUT + o] = r;
    }
}

// ---- global mean pool accumulation
__global__ void k_pool(const float* __restrict__ x, const int* __restrict__ batch,
                       float* __restrict__ gsum, float* __restrict__ gcnt) {
    int idx = blockIdx.x * blockDim.x + threadIdx.x;
    if (idx >= NN * DOUT) return;
    int n = idx >> 5, o = idx & 31;
    int b = batch[n];
    atomicAdd(gsum + b * DOUT + o, x[idx]);
    if (o == 0) atomicAdd(gcnt + b, 1.0f);
}

// ---- final fc
__global__ void k_fc(const float* __restrict__ gsum, const float* __restrict__ gcnt,
                     const float* __restrict__ wfc, const float* __restrict__ bfc,
                     float* __restrict__ out) {
    int g = threadIdx.x;
    if (g >= GG) return;
    float c = gcnt[g]; c = c < 1.f ? 1.f : c;
    float acc = 0.f;
#pragma unroll
    for (int o = 0; o < DOUT; o++) acc += gsum[g * DOUT + o] * wfc[o];
    out[g] = acc / c + bfc[0];
}

extern "C" void kernel_launch(void* const* d_in, const int* in_sizes, int n_in,
                              void* d_out, int out_size, void* d_ws, size_t ws_size,
                              hipStream_t stream) {
    const float* x     = (const float*)d_in[0];
    const float* ea    = (const float*)d_in[1];
    const int*   ei    = (const int*)d_in[2];
    const int*   batch = (const int*)d_in[3];
    const float* w1_0 = (const float*)d_in[4];
    const float* b1_0 = (const float*)d_in[5];
    const float* g_0  = (const float*)d_in[6];
    const float* be_0 = (const float*)d_in[7];
    const float* w2_0 = (const float*)d_in[8];
    const float* b2_0 = (const float*)d_in[9];
    const float* wr_0 = (const float*)d_in[10];
    const float* bc_0 = (const float*)d_in[11];
    const float* w1_1 = (const float*)d_in[12];
    const float* b1_1 = (const float*)d_in[13];
    const float* g_1  = (const float*)d_in[14];
    const float* be_1 = (const float*)d_in[15];
    const float* w2_1 = (const float*)d_in[16];
    const float* b2_1 = (const float*)d_in[17];
    const float* wr_1 = (const float*)d_in[18];
    const float* bc_1 = (const float*)d_in[19];
    const float* wfc  = (const float*)d_in[20];
    const float* bfc  = (const float*)d_in[21];

    float* ws    = (float*)d_ws;
    int*   cur   = (int*)(ws + OFF_CUR);
    float* gsum  = ws + OFF_GSUM;
    float* gcnt  = ws + OFF_GCNT;
    int*   degc  = (int*)(ws + OFF_DEGC);
    float* mop   = ws + OFF_MOP;
    float* w1f   = ws + OFF_W1F;
    float* b1f   = ws + OFF_B1F;
    int*   row   = (int*)(ws + OFF_ROW);
    int*   csrc  = (int*)(ws + OFF_SRC);
    int*   ceid  = (int*)(ws + OFF_EID);
    float* z     = ws + OFF_Z;
    float* x1    = ws + OFF_X1;
    float* x2    = ws + OFF_X2;

    hipMemsetAsync(ws, 0, (size_t)ZERO_FLOATS * sizeof(float), stream);

    k_moments<<<64, 256, 0, stream>>>(ea, mop);
    k_deg<<<(EE + 255) / 256, 256, 0, stream>>>(ei, degc);
    k_scan<<<1, 256, 0, stream>>>(degc, row);
    k_scatter<<<(EE + 255) / 256, 256, 0, stream>>>(ei, row, cur, csrc, ceid);

    // ---- layer 0 (din=16)
    k_fold<<<1, 64, 0, stream>>>(mop, w1_0, b1_0, g_0, be_0, w1f, b1f);
    k_z<16><<<NN / 16, 256, 0, stream>>>(x, w2_0, b2_0, z);
    k_edgenode<16><<<NN / 4, 256, 0, stream>>>(ea, row, csrc, ceid, w1f, b1f, z, x, wr_0, bc_0, x1);

    // ---- layer 1 (din=32)
    k_fold<<<1, 64, 0, stream>>>(mop, w1_1, b1_1, g_1, be_1, w1f, b1f);
    k_z<32><<<NN / 16, 256, 0, stream>>>(x1, w2_1, b2_1, z);
    k_edgenode<32><<<NN / 4, 256, 0, stream>>>(ea, row, csrc, ceid, w1f, b1f, z, x1, wr_1, bc_1, x2);

    // ---- pool + fc
    k_pool<<<(NN * DOUT + 255) / 256, 256, 0, stream>>>(x2, batch, gsum, gcnt);
    k_fc<<<1, 128, 0, stream>>>(gsum, gcnt, wfc, bfc, (float*)d_out);
}